// Round 5
// baseline (1011.001 us; speedup 1.0000x reference)
//
#include <hip/hip_runtime.h>

typedef __attribute__((ext_vector_type(8))) __bf16 bf16x8;
typedef __attribute__((ext_vector_type(4))) __bf16 bf16x4;
typedef __attribute__((ext_vector_type(4))) float f32x4;
typedef __attribute__((ext_vector_type(16))) float f32x16;

#define SEQ   4096
#define NIN   1024
#define DH    128
#define NOUTD 1024
#define HEADS 8
#define CPH   1280
#define L2E   1.44269504f

static __device__ inline f32x16 zero16() {
  f32x16 z;
#pragma unroll
  for (int r = 0; r < 16; ++r) z[r] = 0.f;
  return z;
}

static __device__ inline unsigned pk2(float a, float b) {
  unsigned short ua = __builtin_bit_cast(unsigned short, (__bf16)a);
  unsigned short ub = __builtin_bit_cast(unsigned short, (__bf16)b);
  return (unsigned)ua | ((unsigned)ub << 16);
}

// ---------------------------------------------------------------- f32 -> bf16
__global__ __launch_bounds__(256) void k_cvt(const float* __restrict__ src,
                                             __bf16* __restrict__ dst, int n) {
  int i = (blockIdx.x * 256 + threadIdx.x) * 4;
  if (i >= n) return;
  float4 v = *(const float4*)(src + i);
  bf16x4 o = { (__bf16)v.x, (__bf16)v.y, (__bf16)v.z, (__bf16)v.w };
  *(bf16x4*)(dst + i) = o;
}

// ---------------------------------------------------------------- zero d_out
__global__ __launch_bounds__(256) void k_zero(float4* __restrict__ p) {
  p[(size_t)blockIdx.x * 256 + threadIdx.x] = float4{0.f, 0.f, 0.f, 0.f};
}

// ------------------------------------------- GEMM: out = x @ W^T + b, scatter
// Outputs: Kx[h][i][d] (pre-scaled), Q2[h][dg][j][8] (d-octet-major),
//          V2[h][J][e][8] (j-octet-major) — both attn-staging friendly.
__global__ __launch_bounds__(256) void k_gemm_qkv(
    const __bf16* __restrict__ xb, const __bf16* __restrict__ wb,
    const float* __restrict__ bias,
    __bf16* __restrict__ Kx, __bf16* __restrict__ Q2, __bf16* __restrict__ V2)
{
  __shared__ __align__(16) __bf16 As[128 * 32];
  __shared__ __align__(16) __bf16 Bs[128 * 32];
  const int tid = threadIdx.x;
  const int w = tid >> 6, l = tid & 63;
  const int i0 = blockIdx.x * 128;
  const int n0 = blockIdx.y * 128;
  const int lrow = l & 15;
  const int lkb  = (l >> 4) * 16;
  const int soff = (w * 2) * 1024 + l * 16;

  f32x4 acc[4][4] = {};

  for (int kt = 0; kt < 32; ++kt) {
    __syncthreads();
#pragma unroll
    for (int q = 0; q < 2; ++q) {
      int off = soff + q * 1024;
      int row = off >> 6, kb = off & 63;
      const __bf16* ga = xb + (size_t)(i0 + row) * NIN + kt * 32 + (kb >> 1);
      const __bf16* gb = wb + (size_t)(n0 + row) * NIN + kt * 32 + (kb >> 1);
      __builtin_amdgcn_global_load_lds(
          (const __attribute__((address_space(1))) void*)ga,
          (__attribute__((address_space(3))) void*)((char*)As + (w * 2 + q) * 1024),
          16, 0, 0);
      __builtin_amdgcn_global_load_lds(
          (const __attribute__((address_space(1))) void*)gb,
          (__attribute__((address_space(3))) void*)((char*)Bs + (w * 2 + q) * 1024),
          16, 0, 0);
    }
    __syncthreads();
    bf16x8 af[4], bfr[4];
#pragma unroll
    for (int mi = 0; mi < 4; ++mi)
      af[mi] = *(const bf16x8*)((const char*)As + (((w >> 1) * 64 + mi * 16 + lrow) * 64) + lkb);
#pragma unroll
    for (int ni = 0; ni < 4; ++ni)
      bfr[ni] = *(const bf16x8*)((const char*)Bs + (((w & 1) * 64 + ni * 16 + lrow) * 64) + lkb);
#pragma unroll
    for (int mi = 0; mi < 4; ++mi)
#pragma unroll
      for (int ni = 0; ni < 4; ++ni)
        acc[mi][ni] = __builtin_amdgcn_mfma_f32_16x16x32_bf16(af[mi], bfr[ni], acc[mi][ni], 0, 0, 0);
  }

  const int iw = i0 + (w >> 1) * 64;
  const int nw = n0 + (w & 1) * 64;
  const int lhi = l >> 4;
#pragma unroll
  for (int ni = 0; ni < 4; ++ni) {
    int n = nw + ni * 16 + lrow;
    float bv = bias[n];
    int h = n / CPH;
    int c = n - h * CPH;
    if (c < 128) {
#pragma unroll
      for (int mi = 0; mi < 4; ++mi)
#pragma unroll
        for (int r = 0; r < 4; ++r) {
          int i = iw + mi * 16 + lhi * 4 + r;
          float v = acc[mi][ni][r] + bv;
          Kx[(((size_t)h * SEQ + i) << 7) + c] = (__bf16)(v * 0.08838834764831845f);
        }
    } else if (c < 256) {
      int d = c - 128;
      size_t qEl = ((size_t)(h * 16 + (d >> 3)) << 15) + (size_t)(d & 7);
#pragma unroll
      for (int mi = 0; mi < 4; ++mi)
#pragma unroll
        for (int r = 0; r < 4; ++r) {
          int j = iw + mi * 16 + lhi * 4 + r;
          Q2[qEl + ((size_t)j << 3)] = (__bf16)(acc[mi][ni][r] + bv);
        }
    } else {
      int e = c - 256;
#pragma unroll
      for (int mi = 0; mi < 4; ++mi) {
        int jb = iw + mi * 16 + lhi * 4;
        int J = jb >> 3, js = jb & 7;
        size_t vEl = (((size_t)(h * 512 + J)) << 13) + ((size_t)e << 3) + js;
        bf16x4 pk = { (__bf16)(acc[mi][ni][0] + bv), (__bf16)(acc[mi][ni][1] + bv),
                      (__bf16)(acc[mi][ni][2] + bv), (__bf16)(acc[mi][ni][3] + bv) };
        *(bf16x4*)(V2 + vEl) = pk;
      }
    }
  }
}

// --------------------------------------------------------- pass A: softmax stats
// grid 256 = h(8) x itile(32 of 128 rows). 256 thr, 4 waves x 32 i-rows.
// S^T = mfma(Q_frag, K_frag): i = lane&31 lane-local -> per-lane online m/l.
__global__ __launch_bounds__(256) void k_stats(
    const __bf16* __restrict__ Kx, const __bf16* __restrict__ Q2,
    float* __restrict__ stat_m, float* __restrict__ stat_il)
{
  __shared__ __align__(16) char Qb[2][16384];
  const int tid = threadIdx.x;
  const int w = tid >> 6, l = tid & 63;
  const int l31 = l & 31, hl = l >> 5;
  const int b = blockIdx.x;
  const int h = b >> 5;
  const int i_base = (b & 31) * 128;
  const __bf16* Kh = Kx + ((size_t)h * SEQ << 7);
  const char* q2b = (const char*)Q2 + ((size_t)h << 20);

  bf16x8 kf[8];
#pragma unroll
  for (int c = 0; c < 8; ++c)
    kf[c] = *(const bf16x8*)(Kh + (((size_t)(i_base + 32 * w + l31)) << 7) + c * 16 + hl * 8);

  float m_run = -1e30f, l_run = 0.f;

  // stage Q tile: [dg 16][j 64][16B], chunks s: dg=s>>6, j=s&63
#pragma unroll
  for (int k = 0; k < 4; ++k) {
    int s = tid + k * 256;
    const char* src = q2b + ((size_t)(s >> 6) << 16) + (size_t)(s & 63) * 16;
    __builtin_amdgcn_global_load_lds(
        (const __attribute__((address_space(1))) void*)src,
        (__attribute__((address_space(3))) void*)(Qb[0] + s * 16), 16, 0, 0);
  }
  __syncthreads();

  for (int jt = 0; jt < 64; ++jt) {
    const int cur = jt & 1;
    if (jt < 63) {
      int j0n = (jt + 1) * 64;
#pragma unroll
      for (int k = 0; k < 4; ++k) {
        int s = tid + k * 256;
        const char* src = q2b + ((size_t)(s >> 6) << 16) + (size_t)(j0n + (s & 63)) * 16;
        __builtin_amdgcn_global_load_lds(
            (const __attribute__((address_space(1))) void*)src,
            (__attribute__((address_space(3))) void*)(Qb[cur ^ 1] + s * 16), 16, 0, 0);
      }
    }
    const char* qb = Qb[cur];

    f32x16 s0 = zero16(), s1 = zero16();
#pragma unroll
    for (int c = 0; c < 8; ++c) {
      bf16x8 a0 = *(const bf16x8*)(qb + (((2 * c + hl) * 64 + l31) << 4));
      bf16x8 a1 = *(const bf16x8*)(qb + (((2 * c + hl) * 64 + 32 + l31) << 4));
      s0 = __builtin_amdgcn_mfma_f32_32x32x16_bf16(a0, kf[c], s0, 0, 0, 0);
      s1 = __builtin_amdgcn_mfma_f32_32x32x16_bf16(a1, kf[c], s1, 0, 0, 0);
    }

    float pm = -1e30f;
#pragma unroll
    for (int r = 0; r < 16; ++r) pm = fmaxf(pm, fmaxf(s0[r], s1[r]));
    float mn = fmaxf(m_run, pm);
    l_run *= exp2f((m_run - mn) * L2E);
    float a = 0.f;
#pragma unroll
    for (int r = 0; r < 16; ++r)
      a += exp2f((s0[r] - mn) * L2E) + exp2f((s1[r] - mn) * L2E);
    l_run += a;
    m_run = mn;
    __syncthreads();
  }

  float mp = __shfl_xor(m_run, 32);
  float lp = __shfl_xor(l_run, 32);
  float mf = fmaxf(m_run, mp);
  float lf = l_run * exp2f((m_run - mf) * L2E) + lp * exp2f((mp - mf) * L2E);
  if (hl == 0) {
    int i = i_base + 32 * w + l31;
    stat_m[h * SEQ + i] = mf;
    stat_il[h * SEQ + i] = 1.0f / lf;
  }
}

// --------------------------------------------------------- pass B: P*V
// grid 512 = (h, et 4, it 16). 512 thr, 8 waves = 4 i-slots(64) x 2 e-slots(128).
// Per wave: 64 i x 128 e; Q a-frags and V b-frags each reused 2x from regs.
__global__ __launch_bounds__(512, 2) void k_attn3(
    const __bf16* __restrict__ Kx, const __bf16* __restrict__ Q2,
    const __bf16* __restrict__ V2, const float* __restrict__ stat_m,
    const float* __restrict__ stat_il, float* __restrict__ out)
{
  __shared__ __align__(16) char Qb[2][8192];
  __shared__ __align__(16) char Vb[2][16384];
  __shared__ float s_linv[256];

  const int tid = threadIdx.x;
  const int w = tid >> 6, l = tid & 63;
  const int l31 = l & 31, hl = l >> 5;
  const int islot = w & 3, eslot = w >> 2;

  const int b = blockIdx.x;
  const int et = b & 3;
  const int h = ((b >> 2) & 1) + 2 * (b >> 7);
  const int it = (b >> 3) & 15;
  const int i_base = it * 256, e_base = et * 256;

  const __bf16* Kh = Kx + ((size_t)h * SEQ << 7);
  const char* q2b = (const char*)Q2 + ((size_t)h << 20);
  const char* v2b = (const char*)V2 + ((size_t)(h * 512) << 14) + ((size_t)e_base << 4);

  if (tid < 256) s_linv[tid] = stat_il[h * SEQ + i_base + tid];
  const int iw0 = i_base + islot * 64;
  const float m0 = stat_m[h * SEQ + iw0 + l31];
  const float m1 = stat_m[h * SEQ + iw0 + 32 + l31];

  bf16x8 kf[2][8];
#pragma unroll
  for (int ig = 0; ig < 2; ++ig)
#pragma unroll
    for (int c = 0; c < 8; ++c)
      kf[ig][c] = *(const bf16x8*)(Kh + (((size_t)(iw0 + ig * 32 + l31)) << 7) + c * 16 + hl * 8);

  f32x16 acc[2][4];
#pragma unroll
  for (int ig = 0; ig < 2; ++ig)
#pragma unroll
    for (int n = 0; n < 4; ++n) acc[ig][n] = zero16();

  // prologue stage (jt = 0)
  {
    const char* srcQ = q2b + ((size_t)(tid >> 5) << 16) + (size_t)(tid & 31) * 16;
    __builtin_amdgcn_global_load_lds(
        (const __attribute__((address_space(1))) void*)srcQ,
        (__attribute__((address_space(3))) void*)(Qb[0] + tid * 16), 16, 0, 0);
#pragma unroll
    for (int k = 0; k < 2; ++k) {
      int s = tid + k * 512;
      const char* srcV = v2b + ((size_t)(s >> 8) << 14) + (size_t)(s & 255) * 16;
      __builtin_amdgcn_global_load_lds(
          (const __attribute__((address_space(1))) void*)srcV,
          (__attribute__((address_space(3))) void*)(Vb[0] + s * 16), 16, 0, 0);
    }
  }
  __syncthreads();

  for (int jt = 0; jt < 128; ++jt) {
    const int cur = jt & 1;
    if (jt < 127) {
      const int j0n = (jt + 1) * 32;
      const char* srcQ = q2b + ((size_t)(tid >> 5) << 16) + (size_t)(j0n + (tid & 31)) * 16;
      __builtin_amdgcn_global_load_lds(
          (const __attribute__((address_space(1))) void*)srcQ,
          (__attribute__((address_space(3))) void*)(Qb[cur ^ 1] + tid * 16), 16, 0, 0);
#pragma unroll
      for (int k = 0; k < 2; ++k) {
        int s = tid + k * 512;
        const char* srcV = v2b + ((size_t)((jt + 1) * 4 + (s >> 8)) << 14) + (size_t)(s & 255) * 16;
        __builtin_amdgcn_global_load_lds(
            (const __attribute__((address_space(1))) void*)srcV,
            (__attribute__((address_space(3))) void*)(Vb[cur ^ 1] + s * 16), 16, 0, 0);
      }
    }
    const char* qb = Qb[cur];
    const char* vb = Vb[cur];

    // QK^T: S^T[j 32][i], a-frag shared across both i-groups
    f32x16 s0 = zero16(), s1 = zero16();
#pragma unroll
    for (int c = 0; c < 8; ++c) {
      bf16x8 a0 = *(const bf16x8*)(qb + (((2 * c + hl) * 32 + l31) << 4));
      s0 = __builtin_amdgcn_mfma_f32_32x32x16_bf16(a0, kf[0][c], s0, 0, 0, 0);
      s1 = __builtin_amdgcn_mfma_f32_32x32x16_bf16(a0, kf[1][c], s1, 0, 0, 0);
    }

    // P = exp(S - m), in-register transpose to PV A-frags
    bf16x8 pf[2][2];
#pragma unroll
    for (int ig = 0; ig < 2; ++ig) {
      const f32x16& sv = ig ? s1 : s0;
      const float mi = ig ? m1 : m0;
#pragma unroll
      for (int c2 = 0; c2 < 2; ++c2) {
        const int base = 8 * c2;
        float e0 = exp2f((sv[base + 0] - mi) * L2E);
        float e1 = exp2f((sv[base + 1] - mi) * L2E);
        float e2 = exp2f((sv[base + 2] - mi) * L2E);
        float e3 = exp2f((sv[base + 3] - mi) * L2E);
        float e4 = exp2f((sv[base + 4] - mi) * L2E);
        float e5 = exp2f((sv[base + 5] - mi) * L2E);
        float e6 = exp2f((sv[base + 6] - mi) * L2E);
        float e7 = exp2f((sv[base + 7] - mi) * L2E);
        unsigned WA0 = pk2(e0, e1), WA1 = pk2(e2, e3);
        unsigned WB0 = pk2(e4, e5), WB1 = pk2(e6, e7);
        unsigned send0 = hl ? WA0 : WB0;
        unsigned send1 = hl ? WA1 : WB1;
        unsigned r0 = (unsigned)__shfl_xor((int)send0, 32);
        unsigned r1 = (unsigned)__shfl_xor((int)send1, 32);
        int4 qd;
        qd.x = (int)(hl ? r0 : WA0);
        qd.y = (int)(hl ? r1 : WA1);
        qd.z = (int)(hl ? WB0 : r0);
        qd.w = (int)(hl ? WB1 : r1);
        pf[ig][c2] = __builtin_bit_cast(bf16x8, qd);
      }
    }

    // PV: b-frag shared across both i-groups
#pragma unroll
    for (int c2 = 0; c2 < 2; ++c2)
#pragma unroll
      for (int n = 0; n < 4; ++n) {
        bf16x8 bv = *(const bf16x8*)(vb + (((2 * c2 + hl) * 256 + eslot * 128 + 32 * n + l31) << 4));
        acc[0][n] = __builtin_amdgcn_mfma_f32_32x32x16_bf16(pf[0][c2], bv, acc[0][n], 0, 0, 0);
        acc[1][n] = __builtin_amdgcn_mfma_f32_32x32x16_bf16(pf[1][c2], bv, acc[1][n], 0, 0, 0);
      }
    __syncthreads();
  }

  // epilogue: normalize + atomicAdd across heads
#pragma unroll
  for (int ig = 0; ig < 2; ++ig)
#pragma unroll
    for (int n = 0; n < 4; ++n) {
      const int e = e_base + eslot * 128 + 32 * n + l31;
#pragma unroll
      for (int r = 0; r < 16; ++r) {
        int row = (r & 3) + 8 * (r >> 2) + 4 * hl;
        int iloc = islot * 64 + ig * 32 + row;
        float v = acc[ig][n][r] * s_linv[iloc];
        atomicAdd(out + (((size_t)(i_base + iloc)) << 10) + e, v);
      }
    }
}

// ---------------------------------------------------------------- LayerNorm
__global__ __launch_bounds__(256) void k_ln(float* __restrict__ io,
                                            const float* __restrict__ lw,
                                            const float* __restrict__ lb) {
  const int i = blockIdx.x, t = threadIdx.x;
  const int w = t >> 6, l = t & 63;
  float4 v = *(const float4*)(io + ((size_t)i << 10) + t * 4);
  float s = v.x + v.y + v.z + v.w;
  float q = v.x * v.x + v.y * v.y + v.z * v.z + v.w * v.w;
#pragma unroll
  for (int d = 1; d < 64; d <<= 1) {
    s += __shfl_xor(s, d);
    q += __shfl_xor(q, d);
  }
  __shared__ float red[4][2];
  if (l == 0) { red[w][0] = s; red[w][1] = q; }
  __syncthreads();
  s = red[0][0] + red[1][0] + red[2][0] + red[3][0];
  q = red[0][1] + red[1][1] + red[2][1] + red[3][1];
  float mean = s * (1.0f / 1024.0f);
  float var = q * (1.0f / 1024.0f) - mean * mean;
  float rstd = rsqrtf(var + 1e-5f);
  float4 gw = *(const float4*)(lw + t * 4);
  float4 gb = *(const float4*)(lb + t * 4);
  float4 ov;
  ov.x = (v.x - mean) * rstd * gw.x + gb.x;
  ov.y = (v.y - mean) * rstd * gw.y + gb.y;
  ov.z = (v.z - mean) * rstd * gw.z + gb.z;
  ov.w = (v.w - mean) * rstd * gw.w + gb.w;
  *(float4*)(io + ((size_t)i << 10) + t * 4) = ov;
}

// ---------------------------------------------------------------- launch
extern "C" void kernel_launch(void* const* d_in, const int* in_sizes, int n_in,
                              void* d_out, int out_size, void* d_ws, size_t ws_size,
                              hipStream_t stream) {
  (void)in_sizes; (void)n_in; (void)out_size; (void)ws_size;
  const float* x  = (const float*)d_in[0];
  const float* W  = (const float*)d_in[1];
  const float* b  = (const float*)d_in[2];
  const float* lw = (const float*)d_in[3];
  const float* lb = (const float*)d_in[4];
  float* out = (float*)d_out;
  char* ws = (char*)d_ws;

  __bf16* xb = (__bf16*)ws;                                    //  8 MB (dead after GEMM)
  __bf16* wb = (__bf16*)(ws + (size_t)8  * 1024 * 1024);       // 20 MB
  __bf16* Kx = (__bf16*)(ws + (size_t)28 * 1024 * 1024);       //  8 MB
  __bf16* Q2 = (__bf16*)(ws + (size_t)36 * 1024 * 1024);       //  8 MB
  __bf16* V2 = (__bf16*)(ws + (size_t)44 * 1024 * 1024);       // 64 MB
  float* stat_m  = (float*)ws;                                 // reuse xb
  float* stat_il = (float*)(ws + (size_t)128 * 1024);

  k_cvt<<<4096, 256, 0, stream>>>(x, xb, SEQ * NIN);
  k_cvt<<<10240, 256, 0, stream>>>(W, wb, HEADS * CPH * NIN);
  k_gemm_qkv<<<dim3(32, 80), 256, 0, stream>>>(xb, wb, b, Kx, Q2, V2);
  k_zero<<<4096, 256, 0, stream>>>((float4*)out);
  k_stats<<<256, 256, 0, stream>>>(Kx, Q2, stat_m, stat_il);
  k_attn3<<<512, 512, 0, stream>>>(Kx, Q2, V2, stat_m, stat_il, out);
  k_ln<<<4096, 256, 0, stream>>>(out, lw, lb);
}